// Round 8
// baseline (265.597 us; speedup 1.0000x reference)
//
#include <hip/hip_runtime.h>
#include <hip/hip_bf16.h>
#include <math.h>

#define INPUT_DIM 256
#define OUT_DIM   256
#define NDEG      8                    // degree+1
#define KTOT      (INPUT_DIM * NDEG)   // 2048
#define NROWS     (16 * 2048)          // 32768

#define BM  64                         // block rows (featurize exactly once globally)
#define BK  64                         // 8 inputs * 8 degrees per K-chunk
#define NK  (KTOT / BK)                // 32
#define CHUNK_ELEMS 16384              // full-width B chunk: 256 o * 64 k

typedef __bf16 bf16x8 __attribute__((ext_vector_type(8)));
typedef float  f32x16 __attribute__((ext_vector_type(16)));

// ---------------------------------------------------------------------------
// Kernel 1: reorder coeffs C[i][o][d] (fp32) -> B pages (bf16).
// Page = one wave-frag load: 1 KB, lane(h=lane>>5, l31) entry 16 B.
//   elem = kc*16384 + (s*4 + c)*1024 + ni*512 + h*256 + l31*8 + r
//   (kc=i>>3, s=(i&7)>>1, h=i&1, c=o>>6, ni=(o>>5)&1, l31=o&31, r=d)
// GEMM-side frag read = global_load_dwordx4 at page + lane*16B, fully
// coalesced, L2/L1-resident (1 MB total).
// ---------------------------------------------------------------------------
__global__ __launch_bounds__(256) void reorder_coeffs(const float* __restrict__ C,
                                                      __bf16* __restrict__ Bt) {
    int g = blockIdx.x * 256 + threadIdx.x;   // 65536 = 256 i * 256 o
    int i = g >> 8;
    int o = g & 255;
    const float4* src = (const float4*)(C + (size_t)i * (OUT_DIM * NDEG) + o * NDEG);
    float4 a = src[0];
    float4 b = src[1];
    bf16x8 v;
    v[0] = (__bf16)a.x; v[1] = (__bf16)a.y; v[2] = (__bf16)a.z; v[3] = (__bf16)a.w;
    v[4] = (__bf16)b.x; v[5] = (__bf16)b.y; v[6] = (__bf16)b.z; v[7] = (__bf16)b.w;
    int kc = i >> 3;
    int p  = i & 7;
    int s  = p >> 1;
    int h  = p & 1;
    int c  = o >> 6;
    int ni = (o >> 5) & 1;
    int l31 = o & 31;
    size_t dst = (size_t)kc * CHUNK_ELEMS + (s * 4 + c) * 1024 + ni * 512 + h * 256 + l31 * 8;
    *(bf16x8*)(Bt + dst) = v;   // 16B-aligned
}

// tanh + physicists' Hermite recurrence -> 8 degrees as bf16x8
__device__ __forceinline__ bf16x8 featurize(float xs) {
    float e = __expf(2.0f * xs);            // tanh(x)=1-2/(e^{2x}+1), robust all x
    float t = 1.0f - 2.0f / (e + 1.0f);
    bf16x8 v;
    float hm2 = 1.0f;                       // H_0
    float hm1 = 2.0f * t;                   // H_1
    v[0] = (__bf16)hm2;
    v[1] = (__bf16)hm1;
    #pragma unroll
    for (int d = 2; d < 8; ++d) {
        float h = 2.0f * t * hm1 - 2.0f * (float)(d - 1) * hm2;
        v[d] = (__bf16)h;
        hm2 = hm1; hm1 = h;
    }
    return v;
}

// ---------------------------------------------------------------------------
// Kernel 2 (Round 8): LDS-light pipeline.
//  - B: NEVER in LDS. Direct L2->VGPR page loads (1 KB coalesced bursts),
//    register double-buffered, issued one full iteration ahead. Kills the
//    LDS-read floor that pinned R4/R5/R6 at ~55 us (1.6 GB LDS reads).
//  - A: featurized ONCE (no redundancy) into LDS dbuf, page layout == frag
//    layout (R7-validated 32x32x16 A-operand mapping), 1 barrier/iter.
//    A-only LDS reads = 0.26 GB (~5 us) vs MFMA floor 13.8 us.
//  - Barrier vmcnt drain harmless: outstanding VMEM at barrier (B/x for
//    kc+1) had the whole MFMA phase to land.
// Block 256 thr / 4 waves, tile 64x256, wave tile 64x64 (2x2 of 32x32x16).
// Grid 512 = 2 blocks/CU.
// ---------------------------------------------------------------------------
__global__ __launch_bounds__(256, 2) void hermite_mfma(const float* __restrict__ x,
                                                       const __bf16* __restrict__ Bt,
                                                       float* __restrict__ out) {
    __shared__ __align__(16) __bf16 Alds[2][4096];   // [buf][p*512 + m*8 + r], 16 KB

    const int tid  = threadIdx.x;
    const int bm   = blockIdx.x;       // 0..511
    const int wave = tid >> 6;         // 0..3 = column slice c
    const int lane = tid & 63;
    const int l31  = lane & 31;
    const int h    = lane >> 5;

    // Featurize mapping: thread -> (row m, input pair pg*2+{0,1}); 1x global.
    const int m  = tid & 63;
    const int pg = tid >> 6;
    const float* xptr = x + (size_t)(bm * BM + m) * INPUT_DIM + pg * 2;

    // B pages for this wave (c = wave): frag(kc,s,ni) at
    //   Bt + kc*16384 + (s*4+wave)*1024 + ni*512 + lane*8
    const __bf16* bbase = Bt + (size_t)wave * 1024 + lane * 8;

    f32x16 acc[2][2] = {};
    bf16x8 bfr[2][4][2];               // [buf][s][ni] = 64 VGPRs

    // ---- prologue: chunk 0 ----
    float2 xv = *(const float2*)(xptr);                 // chunk 0 x
    #pragma unroll
    for (int s = 0; s < 4; ++s)
        #pragma unroll
        for (int ni = 0; ni < 2; ++ni)
            bfr[0][s][ni] = *(const bf16x8*)(bbase + s * 4096 + ni * 512);
    *(bf16x8*)(&Alds[0][(pg * 2 + 0) * 512 + m * 8]) = featurize(xv.x);
    *(bf16x8*)(&Alds[0][(pg * 2 + 1) * 512 + m * 8]) = featurize(xv.y);
    xv = *(const float2*)(xptr + 8);                    // chunk 1 x
    __syncthreads();

    for (int kc = 0; kc < NK; ++kc) {
        const int buf  = kc & 1;
        const int nbuf = buf ^ 1;

        if (kc + 1 < NK) {
            // ---- B(kc+1) -> reg dbuf: 8 coalesced 1 KB bursts, consumed next iter ----
            const __bf16* g = bbase + (size_t)(kc + 1) * CHUNK_ELEMS;
            #pragma unroll
            for (int s = 0; s < 4; ++s)
                #pragma unroll
                for (int ni = 0; ni < 2; ++ni)
                    bfr[nbuf][s][ni] = *(const bf16x8*)(g + s * 4096 + ni * 512);

            // ---- featurize chunk kc+1 -> Alds[nbuf] (consumes xv, loaded last iter) ----
            *(bf16x8*)(&Alds[nbuf][(pg * 2 + 0) * 512 + m * 8]) = featurize(xv.x);
            *(bf16x8*)(&Alds[nbuf][(pg * 2 + 1) * 512 + m * 8]) = featurize(xv.y);

            // ---- x for chunk kc+2 (issued last; consumed next-iter featurize) ----
            int kn = (kc + 2 < NK) ? kc + 2 : NK - 1;
            xv = *(const float2*)(xptr + kn * 8);
        }

        // ---- MFMA chunk kc: 4 k-steps of 16, 2x2 frags of 32x32x16 ----
        #pragma unroll
        for (int s = 0; s < 4; ++s) {
            bf16x8 af0 = *(const bf16x8*)(&Alds[buf][(2 * s + h) * 512 + 0 * 256 + l31 * 8]);
            bf16x8 af1 = *(const bf16x8*)(&Alds[buf][(2 * s + h) * 512 + 1 * 256 + l31 * 8]);
            acc[0][0] = __builtin_amdgcn_mfma_f32_32x32x16_bf16(af0, bfr[buf][s][0], acc[0][0], 0, 0, 0);
            acc[0][1] = __builtin_amdgcn_mfma_f32_32x32x16_bf16(af0, bfr[buf][s][1], acc[0][1], 0, 0, 0);
            acc[1][0] = __builtin_amdgcn_mfma_f32_32x32x16_bf16(af1, bfr[buf][s][0], acc[1][0], 0, 0, 0);
            acc[1][1] = __builtin_amdgcn_mfma_f32_32x32x16_bf16(af1, bfr[buf][s][1], acc[1][1], 0, 0, 0);
        }

        __syncthreads();   // one barrier/iter; outstanding B/x had full MFMA phase to land
    }

    // ---- epilogue: 32x32 C/D col=lane&31, row=(reg&3)+8*(reg>>2)+4*h (R7-validated) ----
    #pragma unroll
    for (int mi = 0; mi < 2; ++mi)
        #pragma unroll
        for (int ni = 0; ni < 2; ++ni) {
            #pragma unroll
            for (int r = 0; r < 16; ++r) {
                int rl  = (r & 3) + 8 * (r >> 2) + 4 * h;
                int row = bm * BM + mi * 32 + rl;
                out[(size_t)row * OUT_DIM + wave * 64 + ni * 32 + l31] = acc[mi][ni][r];
            }
        }
}

// ---------------------------------------------------------------------------
extern "C" void kernel_launch(void* const* d_in, const int* in_sizes, int n_in,
                              void* d_out, int out_size, void* d_ws, size_t ws_size,
                              hipStream_t stream) {
    const float* x = (const float*)d_in[0];          // [16,2048,256] fp32
    const float* C = (const float*)d_in[1];          // [256,256,8]  fp32
    float* out = (float*)d_out;                      // [16,2048,256] fp32
    __bf16* Bt = (__bf16*)d_ws;                      // paged [32][16384] bf16, 1 MB

    reorder_coeffs<<<dim3((INPUT_DIM * OUT_DIM) / 256), dim3(256), 0, stream>>>(C, Bt);
    hermite_mfma<<<dim3(NROWS / BM), dim3(256), 0, stream>>>(x, Bt, out);
}

// Round 9
// 117.947 us; speedup vs baseline: 2.2518x; 2.2518x over previous
//
#include <hip/hip_runtime.h>
#include <hip/hip_bf16.h>
#include <math.h>

#define INPUT_DIM 256
#define OUT_DIM   256
#define NDEG      8                    // degree+1
#define KTOT      (INPUT_DIM * NDEG)   // 2048
#define NROWS     (16 * 2048)          // 32768

#define BM  64                         // block rows (featurize exactly once globally)
#define BK  64                         // 8 inputs * 8 degrees per K-chunk
#define NK  (KTOT / BK)                // 32
#define CHUNK_ELEMS 16384              // full-width B chunk: 256 o * 64 k

typedef __bf16 bf16x8 __attribute__((ext_vector_type(8)));
typedef float  f32x16 __attribute__((ext_vector_type(16)));

// ---------------------------------------------------------------------------
// Kernel 1: reorder coeffs C[i][o][d] (fp32) -> B pages (bf16).
// Page = one wave-frag load: 1 KB, lane entry (h=lane>>5, l31) 16 B:
//   elem = kc*16384 + (s*4 + c)*1024 + ni*512 + h*256 + l31*8 + r
//   (kc=i>>3, s=(i&7)>>1, h=i&1, c=o>>6, ni=(o>>5)&1, l31=o&31, r=d)
// GEMM-side frag read = one coalesced global_load_dwordx4 burst (1 KB/wave),
// L2-resident (Bt = 1 MB total).
// ---------------------------------------------------------------------------
__global__ __launch_bounds__(256) void reorder_coeffs(const float* __restrict__ C,
                                                      __bf16* __restrict__ Bt) {
    int g = blockIdx.x * 256 + threadIdx.x;   // 65536 = 256 i * 256 o
    int i = g >> 8;
    int o = g & 255;
    const float4* src = (const float4*)(C + (size_t)i * (OUT_DIM * NDEG) + o * NDEG);
    float4 a = src[0];
    float4 b = src[1];
    bf16x8 v;
    v[0] = (__bf16)a.x; v[1] = (__bf16)a.y; v[2] = (__bf16)a.z; v[3] = (__bf16)a.w;
    v[4] = (__bf16)b.x; v[5] = (__bf16)b.y; v[6] = (__bf16)b.z; v[7] = (__bf16)b.w;
    int kc = i >> 3;
    int p  = i & 7;
    int s  = p >> 1;
    int h  = p & 1;
    int c  = o >> 6;
    int ni = (o >> 5) & 1;
    int l31 = o & 31;
    size_t dst = (size_t)kc * CHUNK_ELEMS + (s * 4 + c) * 1024 + ni * 512 + h * 256 + l31 * 8;
    *(bf16x8*)(Bt + dst) = v;   // 16B-aligned
}

// tanh + physicists' Hermite recurrence -> 8 degrees as bf16x8
__device__ __forceinline__ bf16x8 featurize(float xs) {
    float e = __expf(2.0f * xs);            // tanh(x)=1-2/(e^{2x}+1), robust all x
    float t = 1.0f - 2.0f / (e + 1.0f);
    bf16x8 v;
    float hm2 = 1.0f;                       // H_0
    float hm1 = 2.0f * t;                   // H_1
    v[0] = (__bf16)hm2;
    v[1] = (__bf16)hm1;
    #pragma unroll
    for (int d = 2; d < 8; ++d) {
        float h = 2.0f * t * hm1 - 2.0f * (float)(d - 1) * hm2;
        v[d] = (__bf16)h;
        hm2 = hm1; hm1 = h;
    }
    return v;
}

// ---------------------------------------------------------------------------
// Kernel 2 (Round 9): R8 architecture, spill-free.
//  R8's B register double-buffer bfr[buf][..] with runtime buf forced the
//  compiler to allocate it in SCRATCH (WRITE_SIZE 549 MB, VGPR=52). Fix:
//  two NAMED buffers + K-loop advanced by 2, so every register index is
//  compile-time. Architecture unchanged:
//  - B: L2 -> VGPR page loads (1 KB coalesced bursts), prefetched one full
//    iteration ahead (~600 cyc of MFMA+VALU covers ~200 cyc L2 latency).
//  - A: featurized once into LDS dbuf (page layout == 32x32x16 A-operand
//    frag layout, R7-validated), one barrier/iter.
//  - LDS reads = A only (0.26 GB ≈ 5 us) — the R4-R6 55-us LDS floor is gone.
// Block 256 thr / 4 waves, tile 64x256, wave tile 64x64 (2x2 of 32x32x16).
// Grid 512 = 2 blocks/CU.
// ---------------------------------------------------------------------------
__global__ __launch_bounds__(256, 2) void hermite_mfma(const float* __restrict__ x,
                                                       const __bf16* __restrict__ Bt,
                                                       float* __restrict__ out) {
    __shared__ __align__(16) __bf16 Alds[2][4096];   // [buf][p*512 + m*8 + r], 16 KB

    const int tid  = threadIdx.x;
    const int bm   = blockIdx.x;       // 0..511
    const int wave = tid >> 6;         // 0..3 = column slice c
    const int lane = tid & 63;
    const int l31  = lane & 31;
    const int h    = lane >> 5;

    // Featurize mapping: thread -> (row m, input pair pg*2+{0,1}); 1x global.
    const int m  = tid & 63;
    const int pg = tid >> 6;
    const float* xptr = x + (size_t)(bm * BM + m) * INPUT_DIM + pg * 2;

    // B pages for this wave (c = wave): frag(kc,s,ni) at
    //   Bt + kc*16384 + (s*4+wave)*1024 + ni*512 + lane*8
    const __bf16* bbase = Bt + (size_t)wave * 1024 + lane * 8;

    f32x16 acc[2][2] = {};
    bf16x8 bfr0[4][2];                 // chunk buffer A (static names: no scratch)
    bf16x8 bfr1[4][2];                 // chunk buffer B

    // ---- prologue: chunk 0 ----
    float2 xv = *(const float2*)(xptr);
    #pragma unroll
    for (int s = 0; s < 4; ++s)
        #pragma unroll
        for (int ni = 0; ni < 2; ++ni)
            bfr0[s][ni] = *(const bf16x8*)(bbase + s * 4096 + ni * 512);
    *(bf16x8*)(&Alds[0][(pg * 2 + 0) * 512 + m * 8]) = featurize(xv.x);
    *(bf16x8*)(&Alds[0][(pg * 2 + 1) * 512 + m * 8]) = featurize(xv.y);
    xv = *(const float2*)(xptr + 8);   // chunk 1 x
    __syncthreads();

    // One pipeline step; CUR/NXT and CB/NB are compile-time per expansion.
#define STEP(KC, CUR, NXT, CB, NB)                                           \
    {                                                                        \
        if ((KC) + 1 < NK) {                                                 \
            const __bf16* g = bbase + (size_t)((KC) + 1) * CHUNK_ELEMS;      \
            _Pragma("unroll")                                                \
            for (int s = 0; s < 4; ++s) {                                    \
                NXT[s][0] = *(const bf16x8*)(g + s * 4096);                  \
                NXT[s][1] = *(const bf16x8*)(g + s * 4096 + 512);            \
            }                                                                \
            *(bf16x8*)(&Alds[NB][(pg * 2 + 0) * 512 + m * 8]) = featurize(xv.x); \
            *(bf16x8*)(&Alds[NB][(pg * 2 + 1) * 512 + m * 8]) = featurize(xv.y); \
            int kn = ((KC) + 2 < NK) ? (KC) + 2 : NK - 1;                    \
            xv = *(const float2*)(xptr + kn * 8);                            \
        }                                                                    \
        _Pragma("unroll")                                                    \
        for (int s = 0; s < 4; ++s) {                                        \
            bf16x8 af0 = *(const bf16x8*)(&Alds[CB][(2 * s + h) * 512 + l31 * 8]);       \
            bf16x8 af1 = *(const bf16x8*)(&Alds[CB][(2 * s + h) * 512 + 256 + l31 * 8]); \
            acc[0][0] = __builtin_amdgcn_mfma_f32_32x32x16_bf16(af0, CUR[s][0], acc[0][0], 0, 0, 0); \
            acc[0][1] = __builtin_amdgcn_mfma_f32_32x32x16_bf16(af0, CUR[s][1], acc[0][1], 0, 0, 0); \
            acc[1][0] = __builtin_amdgcn_mfma_f32_32x32x16_bf16(af1, CUR[s][0], acc[1][0], 0, 0, 0); \
            acc[1][1] = __builtin_amdgcn_mfma_f32_32x32x16_bf16(af1, CUR[s][1], acc[1][1], 0, 0, 0); \
        }                                                                    \
        __syncthreads();                                                     \
    }

    for (int kc2 = 0; kc2 < NK; kc2 += 2) {
        STEP(kc2,     bfr0, bfr1, 0, 1);
        STEP(kc2 + 1, bfr1, bfr0, 1, 0);
    }
#undef STEP

    // ---- epilogue: 32x32 C/D col=lane&31, row=(reg&3)+8*(reg>>2)+4*h (R7-validated) ----
    #pragma unroll
    for (int mi = 0; mi < 2; ++mi)
        #pragma unroll
        for (int ni = 0; ni < 2; ++ni) {
            #pragma unroll
            for (int r = 0; r < 16; ++r) {
                int rl  = (r & 3) + 8 * (r >> 2) + 4 * h;
                int row = bm * BM + mi * 32 + rl;
                out[(size_t)row * OUT_DIM + wave * 64 + ni * 32 + l31] = acc[mi][ni][r];
            }
        }
}

// ---------------------------------------------------------------------------
extern "C" void kernel_launch(void* const* d_in, const int* in_sizes, int n_in,
                              void* d_out, int out_size, void* d_ws, size_t ws_size,
                              hipStream_t stream) {
    const float* x = (const float*)d_in[0];          // [16,2048,256] fp32
    const float* C = (const float*)d_in[1];          // [256,256,8]  fp32
    float* out = (float*)d_out;                      // [16,2048,256] fp32
    __bf16* Bt = (__bf16*)d_ws;                      // paged [32][16384] bf16, 1 MB

    reorder_coeffs<<<dim3((INPUT_DIM * OUT_DIM) / 256), dim3(256), 0, stream>>>(C, Bt);
    hermite_mfma<<<dim3(NROWS / BM), dim3(256), 0, stream>>>(x, Bt, out);
}